// Round 4
// baseline (4649.250 us; speedup 1.0000x reference)
//
#include <hip/hip_runtime.h>

// GRU decoder with Bahdanau attention, B=32, T=64, O=E=384, H=768.
// Persistent cooperative kernel, 3 grid barriers per step.
// bf16 weights for attention/FC path (L2-resident per XCD); f32 GRU weights.
// All cross-block mutable traffic via sc0sc1 dwordx4/x2 (no write-combine
// penalty); step-rotated write-once arrays read cached.

#define DEVI static __device__ __forceinline__
typedef float f32x4 __attribute__((ext_vector_type(4)));
typedef unsigned u32x4 __attribute__((ext_vector_type(4)));
typedef unsigned u32x2 __attribute__((ext_vector_type(2)));
typedef unsigned short ushort_t;

constexpr int ATTN_OFF = 786432;

// f32 ws offsets
constexpr int OFF_HALL  = 0;        // 65 x (768k,32b)
constexpr int OFF_U     = 1597440;  // (b,k) 32*768 uncached
constexpr int OFF_WALL  = 1622016;  // 64 x (b,o) f32 w_i
constexpr int OFF_HISTF = 2408448;  // 64 x (b,o) f32 outputs (exact)
constexpr int OFF_GH    = 3194880;  // (row,b) 2304*32 uncached
constexpr int OFF_GIE   = 3268608;  // (row,b) 2304*32 uncached
constexpr int OFF_FE    = 3342336;  // (row,b) 384*32
constexpr int OFF_GE    = 3354624;  // (row,b) 768*32
constexpr int OFF_FP    = 3379200;  // (row,b) 384*32
constexpr int OFF_CP    = 3391488;  // (row,b) 768*32
constexpr int OFF_GB    = 3416064;  // 768
constexpr int OFF_V1    = 3416832;  // 1 (+pad)
constexpr int OFF_BAR   = 3416864;  // 1152 u32
constexpr int OFF_F32END= 3418016;

// ushort offsets (into w16 = (ushort*)(ws + OFF_F32END))
constexpr int O16_AW   = 0;         // attn_W[:, :768]  768*768
constexpr int O16_GHM  = 589824;    // Gh 768*768
constexpr int O16_FCW  = 1179648;   // fcW full 384*1536
constexpr int O16_GWM  = 1769472;   // Gw 768*384
constexpr int O16_GEM  = 2064384;   // Ge 768*384
constexpr int O16_CALL = 2359296;   // 64 x (b,k) bf16 c_t
constexpr int O16_HIST = 3932160;   // 64 x (b,o) bf16 hist_t
// end 4718592 ushorts; total ws = 13.0 MiB f32 + 9.0 MiB bf16

DEVI float fast_tanh(float x) {
  float a = __builtin_fabsf(x);
  float e = __expf(-2.0f * a);
  float r = __fdividef(1.0f - e, 1.0f + e);
  return __builtin_copysignf(r, x);
}
DEVI float sigmoidf_(float x) { return __fdividef(1.0f, 1.0f + __expf(-x)); }

DEVI float bflo(unsigned u) { return __uint_as_float(u << 16); }
DEVI float bfhi(unsigned u) { return __uint_as_float(u & 0xffff0000u); }
DEVI ushort_t f2bf(float f) {
  unsigned u = __float_as_uint(f);
  return (ushort_t)((u + 0x7fffu + ((u >> 16) & 1u)) >> 16);
}

DEVI float nc_ld_f1(const float* p) {
  float r;
  asm volatile("global_load_dword %0, %1, off sc0 sc1\n\ts_waitcnt vmcnt(0)"
               : "=&v"(r) : "v"(p) : "memory");
  return r;
}
DEVI f32x4 nc_ld4(const float* p) {
  f32x4 r;
  asm volatile("global_load_dwordx4 %0, %1, off sc0 sc1\n\ts_waitcnt vmcnt(0)"
               : "=&v"(r) : "v"(p) : "memory");
  return r;
}
DEVI void nc_st4(float* p, f32x4 v) {
  asm volatile("global_store_dwordx4 %0, %1, off sc0 sc1" :: "v"(p), "v"(v) : "memory");
}
DEVI void nc_st4u(ushort_t* p, u32x4 v) {
  asm volatile("global_store_dwordx4 %0, %1, off sc0 sc1" :: "v"(p), "v"(v) : "memory");
}
DEVI void nc_st2u(ushort_t* p, u32x2 v) {
  asm volatile("global_store_dwordx2 %0, %1, off sc0 sc1" :: "v"(p), "v"(v) : "memory");
}
DEVI void nc_st_f1(float* p, float v_) {
  asm volatile("global_store_dword %0, %1, off sc0 sc1" :: "v"(p), "v"(v_) : "memory");
}

// relaxed-only grid barrier
DEVI void gridbar(unsigned* bar) {
  asm volatile("s_waitcnt vmcnt(0)" ::: "memory");
  __syncthreads();
  if (threadIdx.x == 0) {
    unsigned* super = bar + 1024;
    unsigned* gen   = bar + 1056;
    unsigned g = __hip_atomic_load(gen, __ATOMIC_RELAXED, __HIP_MEMORY_SCOPE_AGENT);
    int grp = (int)(blockIdx.x >> 3);
    unsigned a = __hip_atomic_fetch_add(bar + grp * 32, 1u, __ATOMIC_RELAXED, __HIP_MEMORY_SCOPE_AGENT);
    bool released = false;
    if (a == 7u) {
      __hip_atomic_store(bar + grp * 32, 0u, __ATOMIC_RELAXED, __HIP_MEMORY_SCOPE_AGENT);
      unsigned s = __hip_atomic_fetch_add(super, 1u, __ATOMIC_RELAXED, __HIP_MEMORY_SCOPE_AGENT);
      if (s == 31u) {
        __hip_atomic_store(super, 0u, __ATOMIC_RELAXED, __HIP_MEMORY_SCOPE_AGENT);
        __hip_atomic_fetch_add(gen, 1u, __ATOMIC_RELAXED, __HIP_MEMORY_SCOPE_AGENT);
        released = true;
      }
    }
    if (!released) {
      while (__hip_atomic_load(gen, __ATOMIC_RELAXED, __HIP_MEMORY_SCOPE_AGENT) == g) {
        __builtin_amdgcn_s_sleep(1);
      }
    }
  }
  __syncthreads();
}

DEVI float dot24_f32(const float* wp, const float* xr) {
  float acc = 0.f;
#pragma unroll
  for (int q = 0; q < 6; ++q) {
    f32x4 w = *(const f32x4*)(wp + q * 4);
    acc = fmaf(w[0], xr[q * 4 + 0], acc);
    acc = fmaf(w[1], xr[q * 4 + 1], acc);
    acc = fmaf(w[2], xr[q * 4 + 2], acc);
    acc = fmaf(w[3], xr[q * 4 + 3], acc);
  }
  return acc;
}
DEVI float dot24_bf16(const ushort_t* wp, const float* xr) {
  u32x4 w0 = ((const u32x4*)wp)[0];
  u32x4 w1 = ((const u32x4*)wp)[1];
  u32x4 w2 = ((const u32x4*)wp)[2];
  float acc = 0.f;
#pragma unroll
  for (int j = 0; j < 4; ++j) {
    acc = fmaf(bflo(w0[j]), xr[2 * j], acc);
    acc = fmaf(bfhi(w0[j]), xr[2 * j + 1], acc);
    acc = fmaf(bflo(w1[j]), xr[8 + 2 * j], acc);
    acc = fmaf(bfhi(w1[j]), xr[8 + 2 * j + 1], acc);
    acc = fmaf(bflo(w2[j]), xr[16 + 2 * j], acc);
    acc = fmaf(bfhi(w2[j]), xr[16 + 2 * j + 1], acc);
  }
  return acc;
}

// ---------- weight conversion: AW16, FCW16 ----------
__global__ __launch_bounds__(1024) void kconv(const float* __restrict__ attn_W,
                                              const float* __restrict__ fcW,
                                              float* __restrict__ ws) {
  ushort_t* w16 = (ushort_t*)(ws + OFF_F32END);
  int gt = blockIdx.x * 1024 + threadIdx.x;
  if (gt < 589824) {
    int row = gt / 768, col = gt - row * 768;
    w16[O16_AW + gt] = f2bf(attn_W[row * 1152 + col]);
  } else {
    int idx = gt - 589824;
    w16[O16_FCW + idx] = f2bf(fcW[idx]);
  }
}

// ---------- precompute Gh/Gw/Ge (bf16) + gb ----------
__global__ __launch_bounds__(256) void kprepG(const float* __restrict__ attn_W,
                                              const float* __restrict__ fcW,
                                              const float* __restrict__ fcb,
                                              float* __restrict__ ws) {
  ushort_t* w16 = (ushort_t*)(ws + OFF_F32END);
  int bid = blockIdx.x, tid = threadIdx.x;
  if (bid < 288) {
    int rt = bid / 6, kt = bid % 6;
    int r0 = rt * 16;
    int kg = kt * 256 + tid;
    float acc[16];
#pragma unroll
    for (int q = 0; q < 16; ++q) acc[q] = 0.f;
    for (int o = 0; o < 384; ++o) {
      float f = fcW[o * 1536 + kg];
#pragma unroll
      for (int q = 0; q < 16; ++q)
        acc[q] = fmaf(attn_W[(r0 + q) * 1152 + 768 + o], f, acc[q]);
    }
#pragma unroll
    for (int q = 0; q < 16; ++q) {
      int r = r0 + q;
      if (kg < 768)       w16[O16_GHM + r * 768 + kg] = f2bf(acc[q]);
      else if (kg < 1152) w16[O16_GWM + r * 384 + (kg - 768)] = f2bf(acc[q]);
      else                w16[O16_GEM + r * 384 + (kg - 1152)] = f2bf(acc[q]);
    }
  } else {
    for (int r = tid; r < 768; r += 256) {
      float a = 0.f;
      for (int o = 0; o < 384; ++o) a = fmaf(attn_W[r * 1152 + 768 + o], fcb[o], a);
      ws[OFF_GB + r] = a;
    }
  }
}

// ---------- prep: h transpose, zeros, M, barrier ----------
__global__ __launch_bounds__(256) void kprep0(const float* __restrict__ hidden,
                                              const float* __restrict__ vW,
                                              float* __restrict__ ws) {
  ushort_t* w16 = (ushort_t*)(ws + OFF_F32END);
  int bid = blockIdx.x, tid = threadIdx.x;
  int gtid = bid * 256 + tid;
  if (gtid < 24576) {
    int k = gtid >> 5, b = gtid & 31;
    ws[OFF_HALL + gtid] = hidden[b * 768 + k];
  } else if (gtid < 36864) {
    ((unsigned*)(w16 + O16_CALL))[gtid - 24576] = 0u;
  } else if (gtid < 43008) {
    ((unsigned*)(w16 + O16_HIST))[gtid - 36864] = 0u;
  }
  if (gtid < 1152) ((unsigned*)(ws + OFF_BAR))[gtid] = 0u;
  if (bid == 0) {
    __shared__ float vred[256];
    float a = 0.f;
    for (int k = tid; k < 768; k += 256) a += __builtin_fabsf(vW[k]);
    vred[tid] = a;
    __syncthreads();
    for (int s2 = 128; s2 > 0; s2 >>= 1) {
      if (tid < s2) vred[tid] += vred[tid + s2];
      __syncthreads();
    }
    if (tid == 0) ws[OFF_V1] = vred[0];
  }
}

// ---------- main persistent cooperative kernel ----------
__global__ void __launch_bounds__(1024)
kmain(const int* __restrict__ target, const float* __restrict__ emb,
      const float* __restrict__ attn_b, const float* __restrict__ vW,
      const float* __restrict__ Wih, const float* __restrict__ Whh,
      const float* __restrict__ bih, const float* __restrict__ bhh,
      const float* __restrict__ fcW, const float* __restrict__ fcb,
      float* __restrict__ outp, float* __restrict__ ws) {
  const int bid = blockIdx.x, tid = threadIdx.x;
  const int wv = tid >> 6, lane = tid & 63;
  const int b32 = lane & 31, kh = lane >> 5;
  const int vb = ((bid & 7) << 5) | (bid >> 3);  // XCD-major
  const int xcd = vb >> 5, slot = vb & 31;
  unsigned* bar = (unsigned*)(ws + OFF_BAR);
  ushort_t* w16 = (ushort_t*)(ws + OFF_F32END);

  __shared__ __align__(16) float smem[13536];

  const float Mv = ws[OFF_V1];

  for (int i = 0; i < 64; ++i) {
    // ======== Phase A: u, gh, c_i, out_{i-1} (1056 groups x 4 rows, K=768) ====
    {
      float* part_  = smem;         // 4096
      float* stage  = smem + 4096;  // 256
      float* stage2 = smem + 4352;  // 256
      float xr[24];
      const float* hb = ws + OFF_HALL + i * 24576 + b32;  // (k,b) cached
      const int k0 = wv * 48 + kh * 24;
#pragma unroll
      for (int q = 0; q < 24; ++q) xr[q] = hb[(k0 + q) * 32];

      const int gb = (vb * 1056) >> 8, geE = ((vb + 1) * 1056) >> 8;
      const int nsw = (geE - gb + 1) >> 1;
      for (int sw = 0; sw < nsw; ++sw) {
        const int g0 = gb + sw * 2;
        const int row0 = g0 * 4;
        float a[8];
#pragma unroll
        for (int q = 0; q < 8; ++q) a[q] = 0.f;
#pragma unroll
        for (int gg = 0; gg < 2; ++gg) {
          int g = g0 + gg;
          if (g < geE && !(i == 0 && g >= 768)) {
            if (g >= 192 && g < 768) {
              const float* wp = Whh + ((g - 192) * 4) * 768 + k0;
#pragma unroll
              for (int r = 0; r < 4; ++r) a[gg * 4 + r] = dot24_f32(wp + r * 768, xr);
            } else {
              const ushort_t* wp; int ld;
              if (g < 192)      { wp = w16 + O16_AW + (g * 4) * 768 + k0;            ld = 768;  }
              else if (g < 960) { wp = w16 + O16_GHM + ((g - 768) * 4) * 768 + k0;   ld = 768;  }
              else              { wp = w16 + O16_FCW + ((g - 960) * 4) * 1536 + k0;  ld = 1536; }
#pragma unroll
              for (int r = 0; r < 4; ++r) a[gg * 4 + r] = dot24_bf16(wp + r * ld, xr);
            }
          }
        }
#pragma unroll
        for (int r8 = 0; r8 < 8; ++r8) a[r8] += __shfl_xor(a[r8], 32);
        if (kh == 0) {
#pragma unroll
          for (int r8 = 0; r8 < 8; ++r8) part_[wv * 256 + r8 * 32 + b32] = a[r8];
        }
        __syncthreads();
        if (tid < 256) {
          int rr = tid >> 5, bb = tid & 31;
          int g2 = g0 + (rr >> 2);
          if (g2 < geE && !(i == 0 && g2 >= 768)) {
            float sum = 0.f;
#pragma unroll
            for (int wvv = 0; wvv < 16; ++wvv) sum += part_[wvv * 256 + tid];
            int row = row0 + rr;
            if (row < 768) sum += attn_b[row];
            else if (row < 3072) sum += bhh[row - 768];
            stage[rr * 32 + bb] = sum;
          }
        } else if (tid < 320) {
          int t2 = tid - 256, rr = t2 >> 3, bq = t2 & 7;
          int row = row0 + rr;
          if (row >= 3072 && i > 0 && (g0 + (rr >> 2)) < geE) {
            const float* src = row < 3840 ? ws + OFF_CP + (row - 3072) * 32 + bq * 4
                                          : ws + OFF_FP + (row - 3840) * 32 + bq * 4;
            *(f32x4*)&stage2[rr * 32 + bq * 4] = nc_ld4(src);
          }
        }
        __syncthreads();
        // stores: tid<64 handles both 4-row groups
        if (tid < 64) {
          int gsel = tid >> 5, sub = tid & 31;
          int g2 = g0 + gsel;
          int rows4 = row0 + gsel * 4;
          if (g2 < geE && !(i == 0 && g2 >= 768)) {
            if (rows4 < 768) {
              // U (b,k): per-bb 4 consecutive k
              f32x4 v;
#pragma unroll
              for (int e = 0; e < 4; ++e) v[e] = stage[(gsel * 4 + e) * 32 + sub];
              nc_st4(ws + OFF_U + sub * 768 + rows4, v);
            } else if (rows4 < 3072) {
              // GH (row,b): 4 rows x (8 bq): sub = rr2*8+bq
              int rr2 = sub >> 3, bq = sub & 7;
              f32x4 v;
#pragma unroll
              for (int e = 0; e < 4; ++e) v[e] = stage[(gsel * 4 + rr2) * 32 + bq * 4 + e];
              nc_st4(ws + OFF_GH + (rows4 - 768 + rr2) * 32 + bq * 4, v);
            } else if (rows4 < 3840) {
              if (i > 0) {
                float v0 = stage[(gsel * 4 + 0) * 32 + sub] + stage2[(gsel * 4 + 0) * 32 + sub];
                float v1 = stage[(gsel * 4 + 1) * 32 + sub] + stage2[(gsel * 4 + 1) * 32 + sub];
                float v2 = stage[(gsel * 4 + 2) * 32 + sub] + stage2[(gsel * 4 + 2) * 32 + sub];
                float v3 = stage[(gsel * 4 + 3) * 32 + sub] + stage2[(gsel * 4 + 3) * 32 + sub];
                u32x2 pk;
                pk[0] = (unsigned)f2bf(v0) | ((unsigned)f2bf(v1) << 16);
                pk[1] = (unsigned)f2bf(v2) | ((unsigned)f2bf(v3) << 16);
                nc_st2u(w16 + O16_CALL + i * 24576 + sub * 768 + (rows4 - 3072), pk);
              }
            } else {
              if (i > 0) {
                float v0 = stage[(gsel * 4 + 0) * 32 + sub] + stage2[(gsel * 4 + 0) * 32 + sub];
                float v1 = stage[(gsel * 4 + 1) * 32 + sub] + stage2[(gsel * 4 + 1) * 32 + sub];
                float v2 = stage[(gsel * 4 + 2) * 32 + sub] + stage2[(gsel * 4 + 2) * 32 + sub];
                float v3 = stage[(gsel * 4 + 3) * 32 + sub] + stage2[(gsel * 4 + 3) * 32 + sub];
                u32x2 pk;
                pk[0] = (unsigned)f2bf(v0) | ((unsigned)f2bf(v1) << 16);
                pk[1] = (unsigned)f2bf(v2) | ((unsigned)f2bf(v3) << 16);
                nc_st2u(w16 + O16_HIST + i * 12288 + sub * 384 + (rows4 - 3840), pk);
                f32x4 vf = {v0, v1, v2, v3};
                nc_st4(ws + OFF_HISTF + i * 12288 + sub * 384 + (rows4 - 3840), vf);
              }
            }
          }
        }
        __syncthreads();
      }
    }
    gridbar(bar);

    // ======== Phase B: attention (32 blocks) | gie/fe/ge (224 blocks) ====
    if (slot < 4) {
      const int bb = xcd * 4 + (vb & 3);
      float* u_s  = smem;          // 768
      float* p_l  = smem + 768;    // 64
      float* d_l  = smem + 832;    // 1
      float* wred = smem + 848;    // 768
      if (tid < 192) *(f32x4*)&u_s[tid * 4] = nc_ld4(ws + OFF_U + bb * 768 + tid * 4);
      if (tid < 64) p_l[tid] = 0.f;
      __syncthreads();
      const int tl = tid >> 5, kc = tid & 31;
      float u_r[24], v_r[24];
#pragma unroll
      for (int q = 0; q < 24; ++q) {
        u_r[q] = u_s[kc * 24 + q];
        v_r[q] = vW[kc * 24 + q];
      }
#pragma unroll
      for (int rr2 = 0; rr2 < 2; ++rr2) {
        int t = rr2 * 32 + tl;
        float s = 0.f;
        if (t <= i) {
          const ushort_t* cb = w16 + O16_CALL + t * 24576 + bb * 768 + kc * 24;
          u32x4 c0 = ((const u32x4*)cb)[0];
          u32x4 c1 = ((const u32x4*)cb)[1];
          u32x4 c2 = ((const u32x4*)cb)[2];
#pragma unroll
          for (int j = 0; j < 4; ++j) {
            s = fmaf(fast_tanh(u_r[2 * j] + bflo(c0[j])), v_r[2 * j], s);
            s = fmaf(fast_tanh(u_r[2 * j + 1] + bfhi(c0[j])), v_r[2 * j + 1], s);
            s = fmaf(fast_tanh(u_r[8 + 2 * j] + bflo(c1[j])), v_r[8 + 2 * j], s);
            s = fmaf(fast_tanh(u_r[8 + 2 * j + 1] + bfhi(c1[j])), v_r[8 + 2 * j + 1], s);
            s = fmaf(fast_tanh(u_r[16 + 2 * j] + bflo(c2[j])), v_r[16 + 2 * j], s);
            s = fmaf(fast_tanh(u_r[16 + 2 * j + 1] + bfhi(c2[j])), v_r[16 + 2 * j + 1], s);
          }
        }
#pragma unroll
        for (int d2 = 16; d2 >= 1; d2 >>= 1) s += __shfl_xor(s, d2);
        if (kc == 0 && t <= i) p_l[t] = __expf(s - Mv);
      }
      __syncthreads();
      if (tid == 0) {
        float D = 0.f;
        for (int t = 0; t <= i; ++t) D += p_l[t];
        d_l[0] = __fdividef(1.0f, D);
      }
      __syncthreads();
      float dinv = d_l[0];
      if (tid <= i)
        outp[ATTN_OFF + bb * 2080 + (i * (i + 1)) / 2 + tid] = p_l[tid] * dinv;
      if (tid < 768) {
        int hf = tid >= 384 ? 1 : 0;
        int o = tid - hf * 384;
        float acc = 0.f;
        for (int t = hf; t <= i; t += 2) {
          unsigned hv = (unsigned)w16[O16_HIST + t * 12288 + bb * 384 + o];
          acc = fmaf(p_l[t], __uint_as_float(hv << 16), acc);
        }
        wred[tid] = acc;
      }
      __syncthreads();
      if (tid < 96) {
        f32x4 v;
#pragma unroll
        for (int e = 0; e < 4; ++e) {
          int o = tid * 4 + e;
          v[e] = (wred[o] + wred[384 + o]) * dinv;
        }
        nc_st4(ws + OFF_WALL + i * 12288 + bb * 384 + tid * 4, v);
      }
    } else {
      // gie/fe/ge: 864 groups of 4 rows, K=384 (x = emb)
      float* part_  = smem;         // 2048
      float* stageB = smem + 2048;  // 512
      const int lb = slot - 4;
      const int gb2 = xcd * 108 + (lb * 108) / 28;
      const int ge2 = xcd * 108 + ((lb + 1) * 108) / 28;
      const int gl = wv >> 2, kq = wv & 3;
      const int tok = target[b32 * 65 + i];
      const float* xe = emb + tok * 384 + kq * 96 + kh * 48;
      const int koff = kq * 96 + kh * 48;
      const int nsw2 = (ge2 - gb2 + 3) >> 2;
      for (int sw = 0; sw < nsw2; ++sw) {
        int g = gb2 + sw * 4 + gl;
        float a0 = 0.f, a1 = 0.f, a2 = 0.f, a3 = 0.f;
        if (g < ge2) {
          if (g < 576) {
            const float* wp = Wih + (g * 4) * 768 + koff;
#pragma unroll
            for (int q = 0; q < 12; ++q) {
              f32x4 xq = *(const f32x4*)(xe + q * 4);
              f32x4 w0 = *(const f32x4*)(wp + q * 4);
              f32x4 w1 = *(const f32x4*)(wp + 768 + q * 4);
              f32x4 w2 = *(const f32x4*)(wp + 1536 + q * 4);
              f32x4 w3 = *(const f32x4*)(wp + 2304 + q * 4);
              a0 = fmaf(w0[0], xq[0], a0); a0 = fmaf(w0[1], xq[1], a0);
              a0 = fmaf(w0[2], xq[2], a0); a0 = fmaf(w0[3], xq[3], a0);
              a1 = fmaf(w1[0], xq[0], a1); a1 = fmaf(w1[1], xq[1], a1);
              a1 = fmaf(w1[2], xq[2], a1); a1 = fmaf(w1[3], xq[3], a1);
              a2 = fmaf(w2[0], xq[0], a2); a2 = fmaf(w2[1], xq[1], a2);
              a2 = fmaf(w2[2], xq[2], a2); a2 = fmaf(w2[3], xq[3], a2);
              a3 = fmaf(w3[0], xq[0], a3); a3 = fmaf(w3[1], xq[1], a3);
              a3 = fmaf(w3[2], xq[2], a3); a3 = fmaf(w3[3], xq[3], a3);
            }
          } else {
            const ushort_t* wp; int ld;
            if (g < 672) { wp = w16 + O16_FCW + ((g - 576) * 4) * 1536 + 1152 + koff; ld = 1536; }
            else         { wp = w16 + O16_GEM + ((g - 672) * 4) * 384 + koff;         ld = 384;  }
#pragma unroll
            for (int q = 0; q < 6; ++q) {
              f32x4 x0 = *(const f32x4*)(xe + q * 8);
              f32x4 x1 = *(const f32x4*)(xe + q * 8 + 4);
              u32x4 w0 = *(const u32x4*)(wp + q * 8);
              u32x4 w1 = *(const u32x4*)(wp + ld + q * 8);
              u32x4 w2 = *(const u32x4*)(wp + 2 * ld + q * 8);
              u32x4 w3 = *(const u32x4*)(wp + 3 * ld + q * 8);
              a0 = fmaf(bflo(w0[0]), x0[0], a0); a0 = fmaf(bfhi(w0[0]), x0[1], a0);
              a0 = fmaf(bflo(w0[1]), x0[2], a0); a0 = fmaf(bfhi(w0[1]), x0[3], a0);
              a0 = fmaf(bflo(w0[2]), x1[0], a0); a0 = fmaf(bfhi(w0[2]), x1[1], a0);
              a0 = fmaf(bflo(w0[3]), x1[2], a0); a0 = fmaf(bfhi(w0[3]), x1[3], a0);
              a1 = fmaf(bflo(w1[0]), x0[0], a1); a1 = fmaf(bfhi(w1[0]), x0[1], a1);
              a1 = fmaf(bflo(w1[1]), x0[2], a1); a1 = fmaf(bfhi(w1[1]), x0[3], a1);
              a1 = fmaf(bflo(w1[2]), x1[0], a1); a1 = fmaf(bfhi(w1[2]), x1[1], a1);
              a1 = fmaf(bflo(w1[3]), x1[2], a1); a1 = fmaf(bfhi(w1[3]), x1[3], a1);
              a2 = fmaf(bflo(w2[0]), x0[0], a2); a2 = fmaf(bfhi(w2[0]), x0[1], a2);
              a2 = fmaf(bflo(w2[1]), x0[2], a2); a2 = fmaf(bfhi(w2[1]), x0[3], a2);
              a2 = fmaf(bflo(w2[2]), x1[0], a2); a2 = fmaf(bfhi(w2[2]), x1[1], a2);
              a2 = fmaf(bflo(w2[3]), x1[2], a2); a2 = fmaf(bfhi(w2[3]), x1[3], a2);
              a3 = fmaf(bflo(w3[0]), x0[0], a3); a3 = fmaf(bfhi(w3[0]), x0[1], a3);
              a3 = fmaf(bflo(w3[1]), x0[2], a3); a3 = fmaf(bfhi(w3[1]), x0[3], a3);
              a3 = fmaf(bflo(w3[2]), x1[0], a3); a3 = fmaf(bfhi(w3[2]), x1[1], a3);
              a3 = fmaf(bflo(w3[3]), x1[2], a3); a3 = fmaf(bfhi(w3[3]), x1[3], a3);
            }
          }
        }
        a0 += __shfl_xor(a0, 32); a1 += __shfl_xor(a1, 32);
        a2 += __shfl_xor(a2, 32); a3 += __shfl_xor(a3, 32);
        if (kh == 0) {
          float* pp = part_ + ((gl * 4 + kq) * 4) * 32 + b32;
          pp[0] = a0; pp[32] = a1; pp[64] = a2; pp[96] = a3;
        }
        __syncthreads();
        if (tid < 512) {
          int gl2 = tid >> 7, rr = (tid >> 5) & 3, bb = tid & 31;
          int g2 = gb2 + sw * 4 + gl2;
          if (g2 < ge2) {
            float sum = part_[((gl2 * 4 + 0) * 4 + rr) * 32 + bb]
                      + part_[((gl2 * 4 + 1) * 4 + rr) * 32 + bb]
                      + part_[((gl2 * 4 + 2) * 4 + rr) * 32 + bb]
                      + part_[((gl2 * 4 + 3) * 4 + rr) * 32 + bb];
            int row = g2 * 4 + rr;
            if (row < 2304) sum += bih[row];
            else if (row < 2688) sum += fcb[row - 2304];
            else sum += ws[OFF_GB + (row - 2688)];
            stageB[(gl2 * 4 + rr) * 32 + bb] = sum;
          }
        }
        __syncthreads();
        if (tid < 128) {
          int r16 = tid >> 3, bq = tid & 7;
          int g2 = gb2 + sw * 4 + (r16 >> 2);
          if (g2 < ge2) {
            int row = g2 * 4 + (r16 & 3);
            f32x4 v;
#pragma unroll
            for (int e = 0; e < 4; ++e) v[e] = stageB[r16 * 32 + bq * 4 + e];
            float* dst;
            if (row < 2304) dst = ws + OFF_GIE + row * 32 + bq * 4;
            else if (row < 2688) dst = ws + OFF_FE + (row - 2304) * 32 + bq * 4;
            else dst = ws + OFF_GE + (row - 2688) * 32 + bq * 4;
            nc_st4(dst, v);
          }
        }
        __syncthreads();
      }
    }
    gridbar(bar);

    // ======== Phase C: w staging, giw, fpart/cpart, gates ====
    {
      float* w_lds   = smem;           // 12416
      float* g_lds   = smem + 12416;   // 576
      float* giw_lds = smem + 12992;   // 288
      float* fpst    = smem + 13280;   // 160
      float* gat     = smem + 13440;   // 96
      for (int idx = tid; idx < 3072; idx += 1024) {
        int f = idx * 4;
        int b = f / 384, o = f - b * 384;
        *(f32x4*)&w_lds[b * 388 + o] = *(const f32x4*)(ws + OFF_WALL + i * 12288 + f);
      }
      __syncthreads();
      const int rb = xcd * 144 + ((slot * 144) >> 5);
      const int re = xcd * 144 + (((slot + 1) * 144) >> 5);
      if (wv < 9) {
        int jl = wv / 3, gg = wv % 3;
        int grow = vb * 3 + jl + gg * 768;
        const float* wp = Wih + grow * 768 + 384 + kh * 192;
        const float* xp = w_lds + b32 * 388 + kh * 192;
        float acc = 0.f;
#pragma unroll 8
        for (int q = 0; q < 48; ++q) {
          f32x4 wq4 = *(const f32x4*)(wp + q * 4);
          f32x4 xq4 = *(const f32x4*)(xp + q * 4);
          acc = fmaf(wq4[0], xq4[0], acc); acc = fmaf(wq4[1], xq4[1], acc);
          acc = fmaf(wq4[2], xq4[2], acc); acc = fmaf(wq4[3], xq4[3], acc);
        }
        acc += __shfl_xor(acc, 32);
        if (kh == 0) giw_lds[(jl * 3 + gg) * 32 + b32] = acc;
      } else if (wv < 14) {
        int r = rb + (wv - 9);
        if (r < re) {
          const ushort_t* wp16 = (r < 384)
              ? w16 + O16_FCW + r * 1536 + 768 + kh * 192
              : w16 + O16_GWM + (r - 384) * 384 + kh * 192;
          const float* xp = w_lds + b32 * 388 + kh * 192;
          float acc = 0.f;
#pragma unroll
          for (int q = 0; q < 24; ++q) {
            u32x4 w = *(const u32x4*)(wp16 + q * 8);
            f32x4 x0 = *(const f32x4*)(xp + q * 8);
            f32x4 x1 = *(const f32x4*)(xp + q * 8 + 4);
            acc = fmaf(bflo(w[0]), x0[0], acc); acc = fmaf(bfhi(w[0]), x0[1], acc);
            acc = fmaf(bflo(w[1]), x0[2], acc); acc = fmaf(bfhi(w[1]), x0[3], acc);
            acc = fmaf(bflo(w[2]), x1[0], acc); acc = fmaf(bfhi(w[2]), x1[1], acc);
            acc = fmaf(bflo(w[3]), x1[2], acc); acc = fmaf(bfhi(w[3]), x1[3], acc);
          }
          acc += __shfl_xor(acc, 32);
          if (kh == 0) fpst[(wv - 9) * 32 + b32] = acc;
        }
      } else {
        int idx = tid - 896;  // 0..127
#pragma unroll
        for (int rep = 0; rep < 2; ++rep) {
          int ldi = idx + rep * 128;
          if (ldi < 144) {
            int row = ldi >> 3, bq = ldi & 7;
            int rr2 = row < 9 ? row : row - 9;
            int r = vb * 3 + (rr2 % 3) + (rr2 / 3) * 768;
            const float* src = ws + (row < 9 ? OFF_GIE : OFF_GH) + r * 32 + bq * 4;
            *(f32x4*)&g_lds[row * 32 + bq * 4] = nc_ld4(src);
          }
        }
      }
      __syncthreads();
      if (tid < 96) {
        int jl = tid >> 5, bb = tid & 31;
        int j = vb * 3 + jl;
        float gi_r = g_lds[jl * 32 + bb];
        float gi_z = g_lds[(3 + jl) * 32 + bb];
        float gi_n = g_lds[(6 + jl) * 32 + bb];
        float gh_r = g_lds[(9 + jl) * 32 + bb];
        float gh_z = g_lds[(12 + jl) * 32 + bb];
        float gh_n = g_lds[(15 + jl) * 32 + bb];
        float giw_r = giw_lds[(jl * 3 + 0) * 32 + bb];
        float giw_z = giw_lds[(jl * 3 + 1) * 32 + bb];
        float giw_n = giw_lds[(jl * 3 + 2) * 32 + bb];
        float hold = ws[OFF_HALL + i * 24576 + j * 32 + bb];
        float r_ = sigmoidf_(gi_r + giw_r + gh_r);
        float z_ = sigmoidf_(gi_z + giw_z + gh_z);
        float n_ = fast_tanh(fmaf(r_, gh_n, gi_n + giw_n));
        gat[jl * 32 + bb] = (1.0f - z_) * n_ + z_ * hold;
      } else if (tid >= 96 && tid < 136) {
        int t2 = tid - 96, rl = t2 >> 3, bq = t2 & 7;
        if (rb + rl < re) {
          int r = rb + rl;
          const float* addp = r < 384 ? ws + OFF_FE + r * 32 + bq * 4
                                      : ws + OFF_GE + (r - 384) * 32 + bq * 4;
          f32x4 ad = nc_ld4(addp);
          f32x4 v;
#pragma unroll
          for (int e = 0; e < 4; ++e) v[e] = fpst[rl * 32 + bq * 4 + e] + ad[e];
          float* dst = r < 384 ? ws + OFF_FP + r * 32 + bq * 4
                               : ws + OFF_CP + (r - 384) * 32 + bq * 4;
          nc_st4(dst, v);
        }
      }
      __syncthreads();
      if (tid < 24) {
        int jl3 = tid >> 3, bq = tid & 7;
        f32x4 v;
#pragma unroll
        for (int e = 0; e < 4; ++e) v[e] = gat[jl3 * 32 + bq * 4 + e];
        nc_st4(ws + OFF_HALL + (i + 1) * 24576 + (vb * 3 + jl3) * 32 + bq * 4, v);
      }
    }
    gridbar(bar);
  }

  // ======== epilogue: out_63 = F_h h_64 + fp_63 ====
  if (slot < 3) {
    int o = xcd * 48 + slot * 16 + wv;
    const float* hcol = ws + OFF_HALL + 64 * 24576 + b32;
    const float* wrow = fcW + o * 1536 + kh * 384;
    float acc = 0.f;
#pragma unroll 4
    for (int q = 0; q < 96; ++q) {
      f32x4 wq = *(const f32x4*)(wrow + q * 4);
      int k = kh * 384 + q * 4;
      acc = fmaf(wq[0], hcol[k * 32], acc);
      acc = fmaf(wq[1], hcol[(k + 1) * 32], acc);
      acc = fmaf(wq[2], hcol[(k + 2) * 32], acc);
      acc = fmaf(wq[3], hcol[(k + 3) * 32], acc);
    }
    acc += __shfl_xor(acc, 32);
    if (kh == 0) {
      float fp = nc_ld_f1(ws + OFF_FP + o * 32 + b32);
      outp[b32 * 24576 + o * 64 + 63] = acc + fp;
    }
  }
  // ======== final transpose: outputs[b][o][t], t=0..62 from HISTF ====
  if (tid < 48) {
    int pair = vb * 48 + tid;
    int b = pair / 384, o = pair - b * 384;
    const float* src = ws + OFF_HISTF + b * 384 + o;
    float* dst = outp + b * 24576 + o * 64;
#pragma unroll 7
    for (int t = 0; t < 63; ++t) dst[t] = src[(t + 1) * 12288];
  }
}

extern "C" void kernel_launch(void* const* d_in, const int* in_sizes, int n_in,
                              void* d_out, int out_size, void* d_ws, size_t ws_size,
                              hipStream_t stream) {
  const int*   target = (const int*)d_in[0];
  const float* hidden = (const float*)d_in[1];
  // d_in[2] = teacher_forcing_ratio (== 1, deterministic path)
  const float* emb    = (const float*)d_in[3];
  const float* attn_W = (const float*)d_in[4];
  const float* attn_b = (const float*)d_in[5];
  const float* vW     = (const float*)d_in[6];
  const float* Wih    = (const float*)d_in[7];
  const float* Whh    = (const float*)d_in[8];
  const float* bih    = (const float*)d_in[9];
  const float* bhh    = (const float*)d_in[10];
  const float* fcW    = (const float*)d_in[11];
  const float* fcb    = (const float*)d_in[12];
  float* outp = (float*)d_out;
  float* ws   = (float*)d_ws;

  kconv<<<1152, 1024, 0, stream>>>(attn_W, fcW, ws);
  kprepG<<<289, 256, 0, stream>>>(attn_W, fcW, fcb, ws);
  kprep0<<<256, 256, 0, stream>>>(hidden, vW, ws);

  void* args[] = {(void*)&target, (void*)&emb, (void*)&attn_b, (void*)&vW,
                  (void*)&Wih, (void*)&Whh, (void*)&bih, (void*)&bhh,
                  (void*)&fcW, (void*)&fcb, (void*)&outp, (void*)&ws};
  hipLaunchCooperativeKernel((const void*)kmain, dim3(256), dim3(1024), args, 0, stream);
}

// Round 5
// 2299.865 us; speedup vs baseline: 2.0215x; 2.0215x over previous
//
#include <hip/hip_runtime.h>

// GRU decoder with Bahdanau attention, B=32, T=64, O=E=384, H=768.
// Persistent cooperative kernel, 3 grid barriers per step.
// KEY: all weights (f32) are loaded ONCE into LDS (~98KB/block over 256
// blocks) -> zero per-step weight traffic. Cross-block activations:
// step-rotated write-once arrays (cached reads) + small sc0sc1 arrays.

#define DEVI static __device__ __forceinline__
typedef float f32x4 __attribute__((ext_vector_type(4)));
typedef unsigned u32x4 __attribute__((ext_vector_type(4)));
typedef unsigned u32x2 __attribute__((ext_vector_type(2)));
typedef unsigned short ushort_t;

constexpr int ATTN_OFF = 786432;

// f32 ws offsets
constexpr int OFF_HALL  = 0;        // 65 x (768k,32b) h, rotated
constexpr int OFF_U     = 1597440;  // (b,k) 32*768 uncached
constexpr int OFF_WALL  = 1622016;  // 64 x (b,o) w_i, rotated
constexpr int OFF_HISTF = 2408448;  // 64 x (b,o) f32 outputs, rotated
constexpr int OFF_GH    = 3194880;  // (row,b) 2304*32 uncached
constexpr int OFF_GIE   = 3268608;  // (row,b) 2304*32 uncached
constexpr int OFF_FE    = 3342336;  // (row,b) 384*32 uncached
constexpr int OFF_GE    = 3354624;  // (row,b) 768*32 uncached
constexpr int OFF_FP    = 3379200;  // (row,b) 384*32 uncached
constexpr int OFF_CP    = 3391488;  // (row,b) 768*32 uncached
constexpr int OFF_GHM   = 3416064;  // Gh (768,768) f32
constexpr int OFF_GWM   = 4005888;  // Gw (768,384) f32
constexpr int OFF_GEM   = 4300800;  // Ge (768,384) f32
constexpr int OFF_GB    = 4595712;  // 768
constexpr int OFF_V1    = 4596480;  // M = sum|v|
constexpr int OFF_BAR   = 4596512;  // 1152 u32
constexpr int OFF_F32END= 4597664;
// ushort offsets into w16 = (ushort*)(ws + OFF_F32END)
constexpr int O16_CALL = 0;         // 64 x (b,k) bf16 c_t, rotated
constexpr int O16_HIST = 1572864;   // 64 x (b,o) bf16 hist_t, rotated
// total ws = 22.04 MiB

DEVI float fast_tanh(float x) {
  float a = __builtin_fabsf(x);
  float e = __expf(-2.0f * a);
  float r = __fdividef(1.0f - e, 1.0f + e);
  return __builtin_copysignf(r, x);
}
DEVI float sigmoidf_(float x) { return __fdividef(1.0f, 1.0f + __expf(-x)); }
DEVI float bflo(unsigned u) { return __uint_as_float(u << 16); }
DEVI float bfhi(unsigned u) { return __uint_as_float(u & 0xffff0000u); }
DEVI unsigned f2bf(float f) {
  unsigned u = __float_as_uint(f);
  return (u + 0x7fffu + ((u >> 16) & 1u)) >> 16;
}

DEVI float nc_ld_f1(const float* p) {
  float r;
  asm volatile("global_load_dword %0, %1, off sc0 sc1\n\ts_waitcnt vmcnt(0)"
               : "=&v"(r) : "v"(p) : "memory");
  return r;
}
DEVI f32x4 nc_ld4(const float* p) {
  f32x4 r;
  asm volatile("global_load_dwordx4 %0, %1, off sc0 sc1\n\ts_waitcnt vmcnt(0)"
               : "=&v"(r) : "v"(p) : "memory");
  return r;
}
DEVI void nc_st4(float* p, f32x4 v) {
  asm volatile("global_store_dwordx4 %0, %1, off sc0 sc1" :: "v"(p), "v"(v) : "memory");
}
DEVI void nc_st2u(ushort_t* p, u32x2 v) {
  asm volatile("global_store_dwordx2 %0, %1, off sc0 sc1" :: "v"(p), "v"(v) : "memory");
}
DEVI void nc_st_f1(float* p, float v_) {
  asm volatile("global_store_dword %0, %1, off sc0 sc1" :: "v"(p), "v"(v_) : "memory");
}
DEVI void nc_st_h1(ushort_t* p, unsigned v_) {
  asm volatile("global_store_short %0, %1, off sc0 sc1" :: "v"(p), "v"(v_) : "memory");
}

// relaxed-only grid barrier (no cache maintenance)
DEVI void gridbar(unsigned* bar) {
  asm volatile("s_waitcnt vmcnt(0)" ::: "memory");
  __syncthreads();
  if (threadIdx.x == 0) {
    unsigned* super = bar + 1024;
    unsigned* gen   = bar + 1056;
    unsigned g = __hip_atomic_load(gen, __ATOMIC_RELAXED, __HIP_MEMORY_SCOPE_AGENT);
    int grp = (int)(blockIdx.x >> 3);
    unsigned a = __hip_atomic_fetch_add(bar + grp * 32, 1u, __ATOMIC_RELAXED, __HIP_MEMORY_SCOPE_AGENT);
    bool released = false;
    if (a == 7u) {
      __hip_atomic_store(bar + grp * 32, 0u, __ATOMIC_RELAXED, __HIP_MEMORY_SCOPE_AGENT);
      unsigned s = __hip_atomic_fetch_add(super, 1u, __ATOMIC_RELAXED, __HIP_MEMORY_SCOPE_AGENT);
      if (s == 31u) {
        __hip_atomic_store(super, 0u, __ATOMIC_RELAXED, __HIP_MEMORY_SCOPE_AGENT);
        __hip_atomic_fetch_add(gen, 1u, __ATOMIC_RELAXED, __HIP_MEMORY_SCOPE_AGENT);
        released = true;
      }
    }
    if (!released) {
      while (__hip_atomic_load(gen, __ATOMIC_RELAXED, __HIP_MEMORY_SCOPE_AGENT) == g) {
        __builtin_amdgcn_s_sleep(1);
      }
    }
  }
  __syncthreads();
}

// ---------- precompute Gh/Gw/Ge (f32) + gb ----------
__global__ __launch_bounds__(256) void kprepG(const float* __restrict__ attn_W,
                                              const float* __restrict__ fcW,
                                              const float* __restrict__ fcb,
                                              float* __restrict__ ws) {
  int bid = blockIdx.x, tid = threadIdx.x;
  if (bid < 288) {
    int rt = bid / 6, kt = bid % 6;
    int r0 = rt * 16;
    int kg = kt * 256 + tid;
    float acc[16];
#pragma unroll
    for (int q = 0; q < 16; ++q) acc[q] = 0.f;
    for (int o = 0; o < 384; ++o) {
      float f = fcW[o * 1536 + kg];
#pragma unroll
      for (int q = 0; q < 16; ++q)
        acc[q] = fmaf(attn_W[(r0 + q) * 1152 + 768 + o], f, acc[q]);
    }
#pragma unroll
    for (int q = 0; q < 16; ++q) {
      int r = r0 + q;
      if (kg < 768)       ws[OFF_GHM + r * 768 + kg] = acc[q];
      else if (kg < 1152) ws[OFF_GWM + r * 384 + (kg - 768)] = acc[q];
      else                ws[OFF_GEM + r * 384 + (kg - 1152)] = acc[q];
    }
  } else {
    for (int r = tid; r < 768; r += 256) {
      float a = 0.f;
      for (int o = 0; o < 384; ++o) a = fmaf(attn_W[r * 1152 + 768 + o], fcb[o], a);
      ws[OFF_GB + r] = a;
    }
  }
}

// ---------- prep: h transpose, zeros, M, barrier ----------
__global__ __launch_bounds__(256) void kprep0(const float* __restrict__ hidden,
                                              const float* __restrict__ vW,
                                              float* __restrict__ ws) {
  ushort_t* w16 = (ushort_t*)(ws + OFF_F32END);
  int bid = blockIdx.x, tid = threadIdx.x;
  int gtid = bid * 256 + tid;
  if (gtid < 24576) {
    int k = gtid >> 5, b = gtid & 31;
    ws[OFF_HALL + gtid] = hidden[b * 768 + k];
  } else if (gtid < 36864) {
    ((unsigned*)(w16 + O16_CALL))[gtid - 24576] = 0u;
  } else if (gtid < 43008) {
    ((unsigned*)(w16 + O16_HIST))[gtid - 36864] = 0u;
  }
  if (gtid < 1152) ((unsigned*)(ws + OFF_BAR))[gtid] = 0u;
  if (bid == 0) {
    __shared__ float vred[256];
    float a = 0.f;
    for (int k = tid; k < 768; k += 256) a += __builtin_fabsf(vW[k]);
    vred[tid] = a;
    __syncthreads();
    for (int s2 = 128; s2 > 0; s2 >>= 1) {
      if (tid < s2) vred[tid] += vred[tid + s2];
      __syncthreads();
    }
    if (tid == 0) ws[OFF_V1] = vred[0];
  }
}

DEVI int rowtypeA(int row) {
  return row < 768 ? 0 : (row < 3072 ? 1 : (row < 3840 ? 2 : 3));
}

// ---------- main persistent cooperative kernel ----------
__global__ void __launch_bounds__(1024)
kmain(const int* __restrict__ target, const float* __restrict__ emb,
      const float* __restrict__ attn_W, const float* __restrict__ attn_b,
      const float* __restrict__ vW,
      const float* __restrict__ Wih, const float* __restrict__ Whh,
      const float* __restrict__ bih, const float* __restrict__ bhh,
      const float* __restrict__ fcW, const float* __restrict__ fcb,
      float* __restrict__ outp, float* __restrict__ ws) {
  const int bid = blockIdx.x, tid = threadIdx.x;
  const int wv = tid >> 6, lane = tid & 63;
  const int b32 = lane & 31, kh = lane >> 5;
  const int vb = ((bid & 7) << 5) | (bid >> 3);  // XCD-major
  const int xcd = vb >> 5, slot = vb & 31;
  unsigned* bar = (unsigned*)(ws + OFF_BAR);
  ushort_t* w16 = (ushort_t*)(ws + OFF_F32END);

  // ---- LDS: persistent weights + phase-workspace union (149 KB) ----
  __shared__ __align__(16) float sW_A[17 * 768];   // 52.2 KB
  __shared__ __align__(16) float sW_B[16 * 384];   // 24.6 KB
  __shared__ __align__(16) float sW_C[14 * 384];   // 21.5 KB
  __shared__ __align__(16) float sUn[13536];       // 54.1 KB

  // ---- row partitions ----
  const int rbA = (vb * 4224) >> 8, reA = ((vb + 1) * 4224) >> 8, nA = reA - rbA;
  const int lb  = xcd * 28 + (slot - 4);  // valid when slot>=4
  const int rbB = (slot >= 4) ? (lb * 3456) / 224 : 0;
  const int reB = (slot >= 4) ? ((lb + 1) * 3456) / 224 : 0;
  const int nB  = reB - rbB;
  const int rbC = xcd * 144 + ((slot * 144) >> 5);
  const int reC = xcd * 144 + (((slot + 1) * 144) >> 5);

  // ---- one-time LDS weight load ----
  for (int lr = 0; lr < nA; ++lr) {
    int row = rbA + lr;
    const float* src;
    if (row < 768)       src = attn_W + row * 1152;
    else if (row < 3072) src = Whh + (row - 768) * 768;
    else if (row < 3840) src = ws + OFF_GHM + (row - 3072) * 768;
    else                 src = fcW + (row - 3840) * 1536;
    if (tid < 768) sW_A[lr * 768 + tid] = src[tid];
  }
  if (slot >= 4) {
    for (int lr = 0; lr < nB; ++lr) {
      int row = rbB + lr;
      const float* src;
      if (row < 2304)      src = Wih + row * 768;
      else if (row < 2688) src = fcW + (row - 2304) * 1536 + 1152;
      else                 src = ws + OFF_GEM + (row - 2688) * 384;
      if (tid < 384) sW_B[lr * 384 + tid] = src[tid];
    }
  }
  for (int lr = 0; lr < 14; ++lr) {
    const float* src = nullptr;
    if (lr < 9) {
      int grow = vb * 3 + (lr / 3) + (lr % 3) * 768;  // lr = jl*3+gg
      src = Wih + grow * 768 + 384;
    } else {
      int r = rbC + (lr - 9);
      if (r < reC) src = (r < 384) ? fcW + r * 1536 + 768
                                   : ws + OFF_GWM + (r - 384) * 384;
    }
    if (src && tid < 384) sW_C[lr * 384 + tid] = src[tid];
  }
  __syncthreads();

  const float Mv = ws[OFF_V1];
  const int k0 = wv * 48 + kh * 24;
  const int nswA = (nA + 3) >> 2;

  for (int i = 0; i < 64; ++i) {
    // ======== Phase A: u, gh, c_i, out_{i-1} (rows rbA..reA, K=768) ====
    {
      float* part_  = sUn;          // 2048
      float* stage  = sUn + 2048;   // 128
      float* stage2 = sUn + 2176;   // 128
      float xr[24];
      const float* hb = ws + OFF_HALL + i * 24576 + b32;  // (k,b) cached
#pragma unroll
      for (int q = 0; q < 24; ++q) xr[q] = hb[(k0 + q) * 32];

      for (int sw = 0; sw < nswA; ++sw) {
        const int lr0 = sw * 4;
        const int row0 = rbA + lr0;
        float a[4];
#pragma unroll
        for (int r = 0; r < 4; ++r) {
          int lr = lr0 + r;
          float acc = 0.f;
          if (lr < nA && !(i == 0 && rbA + lr >= 3072)) {
            const float* wp = &sW_A[lr * 768 + k0];
#pragma unroll
            for (int q = 0; q < 6; ++q) {
              f32x4 w = *(const f32x4*)(wp + q * 4);
              acc = fmaf(w[0], xr[q * 4 + 0], acc);
              acc = fmaf(w[1], xr[q * 4 + 1], acc);
              acc = fmaf(w[2], xr[q * 4 + 2], acc);
              acc = fmaf(w[3], xr[q * 4 + 3], acc);
            }
          }
          a[r] = acc;
        }
#pragma unroll
        for (int r = 0; r < 4; ++r) a[r] += __shfl_xor(a[r], 32);
        if (kh == 0) {
#pragma unroll
          for (int r = 0; r < 4; ++r) part_[wv * 128 + r * 32 + b32] = a[r];
        }
        __syncthreads();
        if (tid < 128) {
          int rr = tid >> 5, bb = tid & 31;
          int lr = lr0 + rr;
          float sum = 0.f;
#pragma unroll
          for (int w2 = 0; w2 < 16; ++w2) sum += part_[w2 * 128 + tid];
          if (lr < nA) {
            int row = row0 + rr;
            int tt = rowtypeA(row);
            if (tt == 0) sum += attn_b[row];
            else if (tt == 1) sum += bhh[row - 768];
            stage[rr * 32 + bb] = sum;
          }
        } else if (tid < 160) {
          int t2 = tid - 128, rr = t2 >> 3, bq = t2 & 7;
          int lr = lr0 + rr;
          if (lr < nA && i > 0) {
            int row = row0 + rr;
            if (row >= 3072) {
              const float* src = row < 3840 ? ws + OFF_CP + (row - 3072) * 32 + bq * 4
                                            : ws + OFF_FP + (row - 3840) * 32 + bq * 4;
              *(f32x4*)&stage2[rr * 32 + bq * 4] = nc_ld4(src);
            }
          }
        }
        __syncthreads();
        // stores
        int t0 = rowtypeA(row0);
        bool all4 = (lr0 + 3 < nA);
        bool pure = all4 && (t0 == rowtypeA(row0 + 3));
        if (pure && t0 >= 2 && i == 0) {
          // skip (c_0 / out_{-1})
        } else if (pure && t0 == 0) {
          if (tid < 32) {
            f32x4 v = {stage[tid], stage[32 + tid], stage[64 + tid], stage[96 + tid]};
            nc_st4(ws + OFF_U + tid * 768 + row0, v);
          }
        } else if (pure && t0 == 1) {
          if (tid < 32) {
            int rr = tid >> 3, bq = tid & 7;
            f32x4 v = *(f32x4*)&stage[rr * 32 + bq * 4];
            nc_st4(ws + OFF_GH + (row0 - 768 + rr) * 32 + bq * 4, v);
          }
        } else if (pure && t0 == 2 && !(row0 & 1)) {
          if (tid < 32) {
            float v0 = stage[tid] + stage2[tid];
            float v1 = stage[32 + tid] + stage2[32 + tid];
            float v2 = stage[64 + tid] + stage2[64 + tid];
            float v3 = stage[96 + tid] + stage2[96 + tid];
            u32x2 pk;
            pk[0] = f2bf(v0) | (f2bf(v1) << 16);
            pk[1] = f2bf(v2) | (f2bf(v3) << 16);
            nc_st2u(w16 + O16_CALL + i * 24576 + tid * 768 + (row0 - 3072), pk);
          }
        } else if (pure && t0 == 3 && !(row0 & 3)) {
          if (tid < 32) {
            float v0 = stage[tid] + stage2[tid];
            float v1 = stage[32 + tid] + stage2[32 + tid];
            float v2 = stage[64 + tid] + stage2[64 + tid];
            float v3 = stage[96 + tid] + stage2[96 + tid];
            u32x2 pk;
            pk[0] = f2bf(v0) | (f2bf(v1) << 16);
            pk[1] = f2bf(v2) | (f2bf(v3) << 16);
            nc_st2u(w16 + O16_HIST + i * 12288 + tid * 384 + (row0 - 3840), pk);
            f32x4 vf = {v0, v1, v2, v3};
            nc_st4(ws + OFF_HISTF + i * 12288 + tid * 384 + (row0 - 3840), vf);
          }
        } else {
          if (tid < 128) {
            int rr = tid >> 5, bb = tid & 31;
            int lr = lr0 + rr;
            if (lr < nA) {
              int row = row0 + rr;
              int tt = rowtypeA(row);
              float v = stage[rr * 32 + bb];
              if (tt == 0) {
                nc_st_f1(ws + OFF_U + bb * 768 + row, v);
              } else if (tt == 1) {
                nc_st_f1(ws + OFF_GH + (row - 768) * 32 + bb, v);
              } else if (i > 0) {
                v += stage2[rr * 32 + bb];
                if (tt == 2) {
                  nc_st_h1(w16 + O16_CALL + i * 24576 + bb * 768 + (row - 3072), f2bf(v));
                } else {
                  nc_st_h1(w16 + O16_HIST + i * 12288 + bb * 384 + (row - 3840), f2bf(v));
                  nc_st_f1(ws + OFF_HISTF + i * 12288 + bb * 384 + (row - 3840), v);
                }
              }
            }
          }
        }
        __syncthreads();
      }
    }
    gridbar(bar);

    // ======== Phase B: attention (32 blocks) | gie/fe/ge GEMM (224 blocks) ====
    if (slot < 4) {
      const int bb = xcd * 4 + (vb & 3);
      float* u_s  = sUn;          // 768
      float* p_l  = sUn + 768;    // 64
      float* d_l  = sUn + 832;    // 1
      float* wred = sUn + 848;    // 768
      if (tid < 192) *(f32x4*)&u_s[tid * 4] = nc_ld4(ws + OFF_U + bb * 768 + tid * 4);
      if (tid < 64) p_l[tid] = 0.f;
      __syncthreads();
      const int tl = tid >> 5, kc = tid & 31;
      float u_r[24], v_r[24];
#pragma unroll
      for (int q = 0; q < 24; ++q) {
        u_r[q] = u_s[kc * 24 + q];
        v_r[q] = vW[kc * 24 + q];
      }
#pragma unroll
      for (int rr2 = 0; rr2 < 2; ++rr2) {
        int t = rr2 * 32 + tl;
        float s = 0.f;
        if (t <= i) {
          const ushort_t* cb = w16 + O16_CALL + t * 24576 + bb * 768 + kc * 24;  // cached
          u32x4 c0 = ((const u32x4*)cb)[0];
          u32x4 c1 = ((const u32x4*)cb)[1];
          u32x4 c2 = ((const u32x4*)cb)[2];
#pragma unroll
          for (int j = 0; j < 4; ++j) {
            s = fmaf(fast_tanh(u_r[2 * j] + bflo(c0[j])), v_r[2 * j], s);
            s = fmaf(fast_tanh(u_r[2 * j + 1] + bfhi(c0[j])), v_r[2 * j + 1], s);
            s = fmaf(fast_tanh(u_r[8 + 2 * j] + bflo(c1[j])), v_r[8 + 2 * j], s);
            s = fmaf(fast_tanh(u_r[8 + 2 * j + 1] + bfhi(c1[j])), v_r[8 + 2 * j + 1], s);
            s = fmaf(fast_tanh(u_r[16 + 2 * j] + bflo(c2[j])), v_r[16 + 2 * j], s);
            s = fmaf(fast_tanh(u_r[16 + 2 * j + 1] + bfhi(c2[j])), v_r[16 + 2 * j + 1], s);
          }
        }
#pragma unroll
        for (int d2 = 16; d2 >= 1; d2 >>= 1) s += __shfl_xor(s, d2);
        if (kc == 0 && t <= i) p_l[t] = __expf(s - Mv);
      }
      __syncthreads();
      if (tid == 0) {
        float D = 0.f;
        for (int t = 0; t <= i; ++t) D += p_l[t];
        d_l[0] = __fdividef(1.0f, D);
      }
      __syncthreads();
      float dinv = d_l[0];
      if (tid <= i)
        outp[ATTN_OFF + bb * 2080 + (i * (i + 1)) / 2 + tid] = p_l[tid] * dinv;
      if (tid < 768) {
        int hf = tid >= 384 ? 1 : 0;
        int o = tid - hf * 384;
        float acc = 0.f;
        for (int t = hf; t <= i; t += 2) {
          unsigned hv = (unsigned)w16[O16_HIST + t * 12288 + bb * 384 + o];  // cached
          acc = fmaf(p_l[t], __uint_as_float(hv << 16), acc);
        }
        wred[tid] = acc;
      }
      __syncthreads();
      if (tid < 96) {
        f32x4 v;
#pragma unroll
        for (int e = 0; e < 4; ++e) {
          int o = tid * 4 + e;
          v[e] = (wred[o] + wred[384 + o]) * dinv;
        }
        nc_st4(ws + OFF_WALL + i * 12288 + bb * 384 + tid * 4, v);
      }
    } else {
      float* part_  = sUn;          // 2048
      float* stageB = sUn + 2048;   // 512
      const int gl = wv >> 2, kq = wv & 3;
      const int tok = target[b32 * 65 + i];
      const int koff = kq * 96 + kh * 48;
      const float* xe = emb + tok * 384 + koff;
      f32x4 x_[12];
#pragma unroll
      for (int q = 0; q < 12; ++q) x_[q] = *(const f32x4*)(xe + q * 4);
      float a[4];
#pragma unroll
      for (int r = 0; r < 4; ++r) {
        int lr = gl * 4 + r;
        float acc = 0.f;
        if (lr < nB) {
          const float* wp = &sW_B[lr * 384 + koff];
#pragma unroll
          for (int q = 0; q < 12; ++q) {
            f32x4 w = *(const f32x4*)(wp + q * 4);
            acc = fmaf(w[0], x_[q][0], acc);
            acc = fmaf(w[1], x_[q][1], acc);
            acc = fmaf(w[2], x_[q][2], acc);
            acc = fmaf(w[3], x_[q][3], acc);
          }
        }
        a[r] = acc;
      }
#pragma unroll
      for (int r = 0; r < 4; ++r) a[r] += __shfl_xor(a[r], 32);
      if (kh == 0) {
#pragma unroll
        for (int r = 0; r < 4; ++r)
          part_[((gl * 4 + r) * 4 + kq) * 32 + b32] = a[r];
      }
      __syncthreads();
      if (tid < 512) {
        int glr = tid >> 5, bb = tid & 31;
        if (glr < nB) {
          float sum = part_[(glr * 4 + 0) * 32 + bb] + part_[(glr * 4 + 1) * 32 + bb]
                    + part_[(glr * 4 + 2) * 32 + bb] + part_[(glr * 4 + 3) * 32 + bb];
          int row = rbB + glr;
          if (row < 2304) sum += bih[row];
          else if (row < 2688) sum += fcb[row - 2304];
          else sum += ws[OFF_GB + (row - 2688)];
          stageB[glr * 32 + bb] = sum;
        }
      }
      __syncthreads();
      if (tid < 128) {
        int r16 = tid >> 3, bq = tid & 7;
        if (r16 < nB) {
          int row = rbB + r16;
          f32x4 v = *(f32x4*)&stageB[r16 * 32 + bq * 4];
          float* dst;
          if (row < 2304) dst = ws + OFF_GIE + row * 32 + bq * 4;
          else if (row < 2688) dst = ws + OFF_FE + (row - 2304) * 32 + bq * 4;
          else dst = ws + OFF_GE + (row - 2688) * 32 + bq * 4;
          nc_st4(dst, v);
        }
      }
      __syncthreads();
    }
    gridbar(bar);

    // ======== Phase C: w staging, giw, fpart/cpart, gates ====
    {
      float* w_lds   = sUn;           // 12416 (stride 388)
      float* g_lds   = sUn + 12416;   // 576
      float* giw_lds = sUn + 12992;   // 288
      float* fpst    = sUn + 13280;   // 160
      float* gat     = sUn + 13440;   // 96
      {
        int b = tid >> 5, c = tid & 31;
        const float* src = ws + OFF_WALL + i * 12288 + tid * 12;  // cached coalesced
        float* dst = w_lds + b * 388 + c * 12;
        *(f32x4*)&dst[0] = *(const f32x4*)(src);
        *(f32x4*)&dst[4] = *(const f32x4*)(src + 4);
        *(f32x4*)&dst[8] = *(const f32x4*)(src + 8);
      }
      __syncthreads();
      if (wv < 9) {
        int jl = wv / 3, gg = wv % 3;
        const float* wp = &sW_C[(jl * 3 + gg) * 384 + kh * 192];
        const float* xp = w_lds + b32 * 388 + kh * 192;
        float acc = 0.f;
#pragma unroll 8
        for (int q = 0; q < 48; ++q) {
          f32x4 wq4 = *(const f32x4*)(wp + q * 4);
          f32x4 xq4 = *(const f32x4*)(xp + q * 4);
          acc = fmaf(wq4[0], xq4[0], acc); acc = fmaf(wq4[1], xq4[1], acc);
          acc = fmaf(wq4[2], xq4[2], acc); acc = fmaf(wq4[3], xq4[3], acc);
        }
        acc += __shfl_xor(acc, 32);
        if (kh == 0) giw_lds[(jl * 3 + gg) * 32 + b32] = acc;
      } else if (wv < 14) {
        int r = rbC + (wv - 9);
        if (r < reC) {
          const float* wp = &sW_C[(9 + (wv - 9)) * 384 + kh * 192];
          const float* xp = w_lds + b32 * 388 + kh * 192;
          float acc = 0.f;
#pragma unroll 8
          for (int q = 0; q < 48; ++q) {
            f32x4 wq4 = *(const f32x4*)(wp + q * 4);
            f32x4 xq4 = *(const f32x4*)(xp + q * 4);
            acc = fmaf(wq4[0], xq4[0], acc); acc = fmaf(wq4[1], xq4[1], acc);
            acc = fmaf(wq4[2], xq4[2], acc); acc = fmaf(wq4[3], xq4[3], acc);
          }
          acc += __shfl_xor(acc, 32);
          if (kh == 0) fpst[(wv - 9) * 32 + b32] = acc;
        }
      } else {
        int idx = tid - 896;  // 0..127
#pragma unroll
        for (int rep = 0; rep < 2; ++rep) {
          int ldi = idx + rep * 128;
          if (ldi < 144) {
            int row = ldi >> 3, bq = ldi & 7;
            int rr2 = row < 9 ? row : row - 9;
            int r = vb * 3 + (rr2 % 3) + (rr2 / 3) * 768;
            const float* src = ws + (row < 9 ? OFF_GIE : OFF_GH) + r * 32 + bq * 4;
            *(f32x4*)&g_lds[row * 32 + bq * 4] = nc_ld4(src);
          }
        }
      }
      __syncthreads();
      if (tid < 96) {
        int jl = tid >> 5, bb = tid & 31;
        int j = vb * 3 + jl;
        float gi_r = g_lds[jl * 32 + bb];
        float gi_z = g_lds[(3 + jl) * 32 + bb];
        float gi_n = g_lds[(6 + jl) * 32 + bb];
        float gh_r = g_lds[(9 + jl) * 32 + bb];
        float gh_z = g_lds[(12 + jl) * 32 + bb];
        float gh_n = g_lds[(15 + jl) * 32 + bb];
        float giw_r = giw_lds[(jl * 3 + 0) * 32 + bb];
        float giw_z = giw_lds[(jl * 3 + 1) * 32 + bb];
        float giw_n = giw_lds[(jl * 3 + 2) * 32 + bb];
        float hold = ws[OFF_HALL + i * 24576 + j * 32 + bb];
        float r_ = sigmoidf_(gi_r + giw_r + gh_r);
        float z_ = sigmoidf_(gi_z + giw_z + gh_z);
        float n_ = fast_tanh(fmaf(r_, gh_n, gi_n + giw_n));
        gat[jl * 32 + bb] = (1.0f - z_) * n_ + z_ * hold;
      } else if (tid >= 96 && tid < 136) {
        int t2 = tid - 96, rl = t2 >> 3, bq = t2 & 7;
        int r = rbC + rl;
        if (r < reC) {
          const float* addp = r < 384 ? ws + OFF_FE + r * 32 + bq * 4
                                      : ws + OFF_GE + (r - 384) * 32 + bq * 4;
          f32x4 ad = nc_ld4(addp);
          f32x4 v;
#pragma unroll
          for (int e = 0; e < 4; ++e) v[e] = fpst[rl * 32 + bq * 4 + e] + ad[e];
          float* dst = r < 384 ? ws + OFF_FP + r * 32 + bq * 4
                               : ws + OFF_CP + (r - 384) * 32 + bq * 4;
          nc_st4(dst, v);
        }
      }
      __syncthreads();
      if (tid < 24) {
        int jl3 = tid >> 3, bq = tid & 7;
        f32x4 v = *(f32x4*)&gat[jl3 * 32 + bq * 4];
        nc_st4(ws + OFF_HALL + (i + 1) * 24576 + (vb * 3 + jl3) * 32 + bq * 4, v);
      }
    }
    gridbar(bar);
  }

  // ======== epilogue: out_63 = F_h h_64 + fp_63 ====
  if (slot < 3) {
    int o = xcd * 48 + slot * 16 + wv;
    const float* hcol = ws + OFF_HALL + 64 * 24576 + b32;
    const float* wrow = fcW + o * 1536 + kh * 384;
    float acc = 0.f;
#pragma unroll 4
    for (int q = 0; q < 96; ++q) {
      f32x4 wq = *(const f32x4*)(wrow + q * 4);
      int k = kh * 384 + q * 4;
      acc = fmaf(wq[0], hcol[k * 32], acc);
      acc = fmaf(wq[1], hcol[(k + 1) * 32], acc);
      acc = fmaf(wq[2], hcol[(k + 2) * 32], acc);
      acc = fmaf(wq[3], hcol[(k + 3) * 32], acc);
    }
    acc += __shfl_xor(acc, 32);
    if (kh == 0) {
      float fp = nc_ld_f1(ws + OFF_FP + o * 32 + b32);
      outp[b32 * 24576 + o * 64 + 63] = acc + fp;
    }
  }
  // ======== final transpose: outputs[b][o][t], t=0..62 from HISTF ====
  if (tid < 48) {
    int pair = vb * 48 + tid;
    int b = pair / 384, o = pair - b * 384;
    const float* src = ws + OFF_HISTF + b * 384 + o;
    float* dst = outp + b * 24576 + o * 64;
#pragma unroll 7
    for (int t = 0; t < 63; ++t) dst[t] = src[(t + 1) * 12288];
  }
}

extern "C" void kernel_launch(void* const* d_in, const int* in_sizes, int n_in,
                              void* d_out, int out_size, void* d_ws, size_t ws_size,
                              hipStream_t stream) {
  const int*   target = (const int*)d_in[0];
  const float* hidden = (const float*)d_in[1];
  // d_in[2] = teacher_forcing_ratio (== 1, deterministic path)
  const float* emb    = (const float*)d_in[3];
  const float* attn_W = (const float*)d_in[4];
  const float* attn_b = (const float*)d_in[5];
  const float* vW     = (const float*)d_in[6];
  const float* Wih    = (const float*)d_in[7];
  const float* Whh    = (const float*)d_in[8];
  const float* bih    = (const float*)d_in[9];
  const float* bhh    = (const float*)d_in[10];
  const float* fcW    = (const float*)d_in[11];
  const float* fcb    = (const float*)d_in[12];
  float* outp = (float*)d_out;
  float* ws   = (float*)d_ws;

  kprepG<<<289, 256, 0, stream>>>(attn_W, fcW, fcb, ws);
  kprep0<<<256, 256, 0, stream>>>(hidden, vW, ws);

  void* args[] = {(void*)&target, (void*)&emb, (void*)&attn_W, (void*)&attn_b,
                  (void*)&vW, (void*)&Wih, (void*)&Whh, (void*)&bih, (void*)&bhh,
                  (void*)&fcW, (void*)&fcb, (void*)&outp, (void*)&ws};
  hipLaunchCooperativeKernel((const void*)kmain, dim3(256), dim3(1024), args, 0, stream);
}